// Round 7
// baseline (360.352 us; speedup 1.0000x reference)
//
#include <hip/hip_runtime.h>
#include <hip/hip_bf16.h>

#define NPTS  40960
#define BNPTS 163840   // 4 batches x 40960
#define KNB   16

// packed-weight workspace offsets (in shorts), after f_pc2
#define PK_MLP1 0        // [32][40]  (interleaved slots)
#define PK_FC1  1280     // [64][88]  (log2e folded)
#define PK_FC2  6912     // [64][88]  (log2e folded)
#define PK_L1   12544    // [32][40]  (scale/bias folded, interleaved slots)
#define PK_L2   13824    // [32][40]  (interleaved slots)
#define PK_M1   15104    // [32][88]  (interleaved in 32-ch pairs)
#define PK_M2   17920    // [64][88]
#define PK_W2   23552    // [128][88] (interleaved in 32-ch pairs)
#define PK_WS   34816    // [128][40] (interleaved in 32-ch pairs)
#define PK_TOTAL 39936   // shorts (= 79872 B, 16B-aligned)

using bf16x8 = __attribute__((ext_vector_type(8))) short;
using f32x4  = __attribute__((ext_vector_type(4))) float;

__device__ __forceinline__ unsigned short f2bf(float x) {
    union { float f; unsigned u; } v; v.f = x;
    unsigned r = v.u + 0x7fffu + ((v.u >> 16) & 1u);   // RTNE
    return (unsigned short)(r >> 16);
}
__device__ __forceinline__ float bf2f(unsigned short u) {
    union { unsigned u; float f; } v; v.u = ((unsigned)u) << 16;
    return v.f;
}
__device__ __forceinline__ unsigned pk2(float lo, float hi) {
    union { __hip_bfloat162 h; unsigned u; } v;
    v.h = __float22bfloat162_rn(float2{lo, hi});
    return v.u;
}
__device__ __forceinline__ bf16x8 pack8(float a0, float a1, float a2, float a3,
                                        float a4, float a5, float a6, float a7) {
    union { unsigned u[4]; bf16x8 v; } w;
    w.u[0] = pk2(a0, a1); w.u[1] = pk2(a2, a3);
    w.u[2] = pk2(a4, a5); w.u[3] = pk2(a6, a7);
    return w.v;
}
__device__ __forceinline__ f32x4 mfma16(bf16x8 a, bf16x8 b, f32x4 c) {
    return __builtin_amdgcn_mfma_f32_16x16x32_bf16(a, b, c, 0, 0, 0);
}
// trans ops via builtins: compiler inserts the required trans->VALU wait states
__device__ __forceinline__ float exp2_fast(float x) { return __builtin_amdgcn_exp2f(x); }
__device__ __forceinline__ float rcp_fast(float x)  { return __builtin_amdgcn_rcpf(x); }

// ---------------------------------------------------------------- k_prep: pack weights + xyz->float4 (once)
__global__ __launch_bounds__(256)
void k_prep(const float* __restrict__ wm1, const float* __restrict__ wfc1,
            const float* __restrict__ wfc2,
            const float* __restrict__ wlfa1, const float* __restrict__ slfa1, const float* __restrict__ blfa1,
            const float* __restrict__ wlfa2,
            const float* __restrict__ wam1, const float* __restrict__ wam2,
            const float* __restrict__ w2, const float* __restrict__ wsc,
            const float* __restrict__ xyz,
            unsigned short* __restrict__ pk, float* __restrict__ xyz4)
{
    const int tid = threadIdx.x, blk = blockIdx.x;
    const float LOG2E = 1.4426950408889634f;
    if (blk >= 8) {   // xyz -> float4 pack
        int idx = (blk - 8) * 256 + tid;
        float3 v = *(const float3*)&xyz[(size_t)idx * 3];
        *(float4*)&xyz4[(size_t)idx * 4] = make_float4(v.x, v.y, v.z, 0.f);
        return;
    }
    switch (blk) {
    case 0: // mlp1, even/odd interleaved slots (pk2 stores in k_mlp1)
        for (int t = tid; t < 32 * 32; t += 256) {
            int c = t >> 5, d = t & 31;
            int slot = (d & 1) * 16 + (d >> 1);
            pk[PK_MLP1 + slot * 40 + c] = f2bf(wm1[t]);
        }
        break;
    case 1: // att1 fc, log2e folded
        for (int t = tid; t < 64 * 64; t += 256) {
            int c = t >> 6, d = t & 63;
            pk[PK_FC1 + d * 88 + c] = f2bf(wfc1[t] * LOG2E);
        }
        break;
    case 2: // att2 fc, log2e folded
        for (int t = tid; t < 64 * 64; t += 256) {
            int c = t >> 6, d = t & 63;
            pk[PK_FC2 + d * 88 + c] = f2bf(wfc2[t] * LOG2E);
        }
        break;
    case 3: // lfa1 (s,b folded; bias in K-row 10) + lfa2, even/odd interleaved slots
        for (int t = tid; t < 32 * 32; t += 256) {
            int k = t >> 5, d = t & 31;
            int slot = (d & 1) * 16 + (d >> 1);
            float v1 = k < 10 ? wlfa1[k * 32 + d] * slfa1[d] : (k == 10 ? blfa1[d] : 0.f);
            pk[PK_L1 + slot * 40 + k] = f2bf(v1);
            pk[PK_L2 + slot * 40 + k] = f2bf(wlfa2[k * 32 + d]);
        }
        break;
    case 4: // att1 mlp (NOUT=32), interleaved within 32-ch pair
        for (int t = tid; t < 64 * 32; t += 256) {
            int c = t / 32, d = t % 32;
            int slot = (d & 1) * 16 + (d >> 1);
            pk[PK_M1 + slot * 88 + c] = f2bf(wam1[t]);
        }
        break;
    case 5: // att2 mlp (NOUT=64)
        for (int t = tid; t < 64 * 64; t += 256) {
            int c = t >> 6, d = t & 63;
            int slot = (d >> 5) * 32 + (d & 1) * 16 + ((d & 31) >> 1);
            pk[PK_M2 + slot * 88 + c] = f2bf(wam2[t]);
        }
        break;
    case 6: // mlp2 weights [128][88], interleaved within 32-ch groups (float2 stores in k_out)
        for (int t = tid; t < 64 * 128; t += 256) {
            int c = t >> 7, d = t & 127;
            int slot = (d >> 5) * 32 + (d & 1) * 16 + ((d & 31) >> 1);
            pk[PK_W2 + slot * 88 + c] = f2bf(w2[t]);
        }
        break;
    case 7: // shortcut weights [128][40], same interleave
        for (int t = tid; t < 32 * 128; t += 256) {
            int c = t >> 7, d = t & 127;
            int slot = (d >> 5) * 32 + (d & 1) * 16 + ((d & 31) >> 1);
            pk[PK_WS + slot * 40 + c] = f2bf(wsc[t]);
        }
        break;
    }
}

// ---------------------------------------------------------------- kernel 1: f_pc = cb(feature, mlp1) -> bf16 [pts][32]
__global__ __launch_bounds__(256)
void k_mlp1(const float* __restrict__ feature, const unsigned short* __restrict__ pk,
            const float* __restrict__ s, const float* __restrict__ b,
            unsigned short* __restrict__ f_pc)
{
    const int tid = threadIdx.x;
    const int lid = tid & 63, wv = tid >> 6;
    const int col = lid & 15, quad = lid >> 4;
    bf16x8 B0 = *(const bf16x8*)&pk[PK_MLP1 + col * 40 + quad * 8];         // even ch 2col
    bf16x8 B1 = *(const bf16x8*)&pk[PK_MLP1 + (16 + col) * 40 + quad * 8];  // odd ch 2col+1
    float s0 = s[2 * col], b0 = b[2 * col], s1 = s[2 * col + 1], b1 = b[2 * col + 1];
    for (int itp = 0; itp < 4; itp++) {
        const int p0 = blockIdx.x * 256 + wv * 64 + itp * 16;
        const float* fr = &feature[(size_t)(p0 + col) * 32 + quad * 8];
        float4 u0 = *(const float4*)fr;
        float4 u1 = *(const float4*)(fr + 4);
        bf16x8 a = pack8(u0.x, u0.y, u0.z, u0.w, u1.x, u1.y, u1.z, u1.w);
        f32x4 z = {0.f, 0.f, 0.f, 0.f};
        f32x4 d0 = mfma16(a, B0, z);
        f32x4 d1 = mfma16(a, B1, z);
        #pragma unroll
        for (int r = 0; r < 4; r++) {
            int p = p0 + quad * 4 + r;
            float ye = fmaxf(d0[r] * s0 + b0, 0.f);
            float yo = fmaxf(d1[r] * s1 + b1, 0.f);
            *(unsigned*)&f_pc[(size_t)p * 32 + 2 * col] = pk2(ye, yo);
        }
    }
}

// ---------------------------------------------------------------- attention kernels
// One wave = 16 points. Changes vs R6:
//  * fc double-buffered as TWO DISTINCT __shared__ objects (fcA_s/fcB_s) with an
//    explicit 2-point loop body: LLVM proves no-alias between the buffers, so
//    point t+1's gather/lfa writes reorder freely against point t's softmax reads.
//    (R5's single-object runtime-offset dbuf could not be disambiguated -> no
//    overlap. The WAR drain between iterations was the per-wave serializer.)
template<int NOUT, bool HAS_LFA2>
__global__ __launch_bounds__(256, 4)
void k_att(const float* __restrict__ xyz4, const int* __restrict__ nidx,
           const unsigned short* __restrict__ src,
           const unsigned short* __restrict__ wl1T, const unsigned short* __restrict__ wl2T,
           const float* __restrict__ slfa2, const float* __restrict__ blfa2,
           const unsigned short* __restrict__ wfcT, const unsigned short* __restrict__ wmT,
           const float* __restrict__ smlp, const float* __restrict__ bmlp,
           unsigned short* __restrict__ out)
{
    constexpr int NP = NOUT / 32;
    constexpr int WS = 88;                       // fc row stride in shorts
    __shared__ __align__(16) unsigned short fcA_s[4][16 * WS];   // 11264 B
    __shared__ __align__(16) unsigned short fcB_s[4][16 * WS];   // 11264 B
    __shared__ __align__(16) unsigned short ag_s[4][16 * 72];    // 9216 B
    __shared__ __align__(16) unsigned short nb_s[4][256];        // 2048 B
    __shared__ __align__(16) float cxy_s[4][64];                 // 1024 B

    const int tid = threadIdx.x;
    const int lid = tid & 63, wv = tid >> 6;
    const int col = lid & 15, quad = lid >> 4;

    // ---- fragments: direct global->reg (L2-resident after first blocks)
    bf16x8 Bfc[4][2];
    #pragma unroll
    for (int nt = 0; nt < 4; nt++)
        #pragma unroll
        for (int ks = 0; ks < 2; ks++)
            Bfc[nt][ks] = *(const bf16x8*)&wfcT[(nt * 16 + col) * WS + ks * 32 + quad * 8];
    bf16x8 Bl1e = *(const bf16x8*)&wl1T[col * 40 + quad * 8];
    bf16x8 Bl1o = *(const bf16x8*)&wl1T[(16 + col) * 40 + quad * 8];
    bf16x8 Bl2e{}, Bl2o{};
    float sl2e = 0.f, bl2e = 0.f, sl2o = 0.f, bl2o = 0.f;
    if (HAS_LFA2) {
        Bl2e = *(const bf16x8*)&wl2T[col * 40 + quad * 8];
        Bl2o = *(const bf16x8*)&wl2T[(16 + col) * 40 + quad * 8];
        sl2e = slfa2[2 * col]; bl2e = blfa2[2 * col];
        sl2o = slfa2[2 * col + 1]; bl2o = blfa2[2 * col + 1];
    }
    float sme[NP], bme[NP], smo[NP], bmo[NP];
    #pragma unroll
    for (int tp = 0; tp < NP; tp++) {
        sme[tp] = smlp[tp * 32 + 2 * col]; bme[tp] = bmlp[tp * 32 + 2 * col];
        smo[tp] = smlp[tp * 32 + 2 * col + 1]; bmo[tp] = bmlp[tp * 32 + 2 * col + 1];
    }

    unsigned short* fcA = fcA_s[wv];
    unsigned short* fcB = fcB_s[wv];
    unsigned short* ag  = ag_s[wv];
    unsigned short* nb  = nb_s[wv];
    float*          cxy = cxy_s[wv];

    const int blk = (int)blockIdx.x;
    const int vblk = (blk & 7) * 320 + (blk >> 3);    // XCD swizzle (grid 2560 = 8 x 320)
    const int pbase = vblk * 64 + wv * 16;
    const int pb = (pbase / NPTS) * NPTS;
    const unsigned short* srcb = src + (size_t)pb * 32;
    const float4* x4  = (const float4*)xyz4;
    const float4* x4b = x4 + pb;

    { // stage this wave's 256 neighbor indices (N=40960 fits u16) + 16 center float4s
        int4 t4 = *(const int4*)&nidx[(size_t)pbase * KNB + lid * 4];
        ushort4 u = make_ushort4((unsigned short)t4.x, (unsigned short)t4.y,
                                 (unsigned short)t4.z, (unsigned short)t4.w);
        *(ushort4*)&nb[lid * 4] = u;
        if (lid < 16) *(float4*)&cxy[lid * 4] = x4[pbase + lid];
    }

    const f32x4 z = {0.f, 0.f, 0.f, 0.f};
    bf16x8 vs; float nx = 0.f, ny = 0.f, nz = 0.f;
    { // prefetch iteration 0
        int j = (int)nb[col];
        vs = *(const bf16x8*)(srcb + (size_t)j * 32 + quad * 8);
        if (quad < 2) { float4 t = x4b[j]; nx = t.x; ny = t.y; nz = t.z; }
    }

    auto body = [&](int it, unsigned short* fcb) {
        bf16x8 a0 = vs;                                 // gathered nbr feats: rows=col, k=quad*8..
        *(bf16x8*)&fcb[col * WS + quad * 8] = a0;       // LDS copy only for softmax-weighted sum

        // rel_pos from prefetched neighbor xyz + staged center xyz
        float cx = cxy[it * 4], cy = cxy[it * 4 + 1], cz = cxy[it * 4 + 2];
        float rx = cx - nx, ry = cy - ny, rz = cz - nz;
        float dd = sqrtf(rx * rx + ry * ry + rz * rz);
        float f0 = 0.f, f1 = 0.f, f2 = 0.f, f3 = 0.f, f4 = 0.f, f5 = 0.f, f6 = 0.f, f7 = 0.f;
        if (quad == 0)      { f0 = dd; f1 = rx; f2 = ry; f3 = rz; f4 = cx; f5 = cy; f6 = cz; f7 = nx; }
        else if (quad == 1) { f0 = ny; f1 = nz; f2 = 1.0f; }   // k=10: folded lfa1 bias row
        bf16x8 al = pack8(f0, f1, f2, f3, f4, f5, f6, f7);

        { // prefetch next iteration (clamped; last iter redoes it=15, harmless)
            int itn = it < 15 ? it + 1 : 15;
            int j = (int)nb[itn * 16 + col];
            vs = *(const bf16x8*)(srcb + (size_t)j * 32 + quad * 8);
            if (quad < 2) { float4 t = x4b[j]; nx = t.x; ny = t.y; nz = t.z; }
        }

        { // ---- lfa1 (+ lfa2) -> fcb[:, 32:64]
            f32x4 d0 = mfma16(al, Bl1e, z);
            f32x4 d1 = mfma16(al, Bl1o, z);
            #pragma unroll
            for (int r = 0; r < 4; r++) {
                float ye = fmaxf(d0[r], 0.f);            // scale/bias folded into W
                float yo = fmaxf(d1[r], 0.f);
                *(unsigned*)&fcb[(quad * 4 + r) * WS + 32 + 2 * col] = pk2(ye, yo);
            }
            if (HAS_LFA2) {
                bf16x8 a2 = *(const bf16x8*)&fcb[col * WS + 32 + quad * 8];
                f32x4 e0 = mfma16(a2, Bl2e, z);
                f32x4 e1 = mfma16(a2, Bl2o, z);
                #pragma unroll
                for (int r = 0; r < 4; r++) {
                    float ye = fmaxf(e0[r] * sl2e + bl2e, 0.f);
                    float yo = fmaxf(e1[r] * sl2o + bl2o, 0.f);
                    *(unsigned*)&fcb[(quad * 4 + r) * WS + 32 + 2 * col] = pk2(ye, yo);
                }
            }
        }

        { // ---- logits GEMM (log2e pre-folded) + softmax over 16 nbrs + pooled agg
            bf16x8 a1 = *(const bf16x8*)&fcb[col * WS + 32 + quad * 8];
            #pragma unroll
            for (int nt = 0; nt < 4; nt++) {
                f32x4 L = mfma16(a1, Bfc[nt][1], mfma16(a0, Bfc[nt][0], z));
                float e0 = exp2_fast(L[0]), e1 = exp2_fast(L[1]);
                float e2 = exp2_fast(L[2]), e3 = exp2_fast(L[3]);
                float sden = (e0 + e1) + (e2 + e3);
                const unsigned short* frr = &fcb[quad * 4 * WS + nt * 16 + col];
                float av = e0 * bf2f(frr[0]) + e1 * bf2f(frr[WS]) + e2 * bf2f(frr[2 * WS]) + e3 * bf2f(frr[3 * WS]);
                av   += __shfl_xor(av, 16, 64);
                sden += __shfl_xor(sden, 16, 64);
                av   += __shfl_xor(av, 32, 64);
                sden += __shfl_xor(sden, 32, 64);
                if (quad == 0) ag[it * 72 + nt * 16 + col] = f2bf(av * rcp_fast(sden));
            }
        }
    };

    #pragma unroll 1
    for (int it2 = 0; it2 < 8; it2++) {      // 2 points/iter: even -> fcA, odd -> fcB
        body(it2 * 2,     fcA);
        body(it2 * 2 + 1, fcB);
    }

    // ---- att-MLP batched over the wave's 16 points (full 16-row MFMA)
    {
        bf16x8 am0 = *(const bf16x8*)&ag[col * 72 + quad * 8];
        bf16x8 am1 = *(const bf16x8*)&ag[col * 72 + 32 + quad * 8];
        #pragma unroll
        for (int tp = 0; tp < NP; tp++) {
            bf16x8 Be0, Be1, Bo0, Bo1;
            if constexpr (NOUT == 32) {
                Be0 = *(const bf16x8*)&wmT[col * WS + quad * 8];
                Be1 = *(const bf16x8*)&wmT[col * WS + 32 + quad * 8];
                Bo0 = *(const bf16x8*)&wmT[(16 + col) * WS + quad * 8];
                Bo1 = *(const bf16x8*)&wmT[(16 + col) * WS + 32 + quad * 8];
            } else {
                Be0 = *(const bf16x8*)&wmT[(tp * 32 + col) * WS + quad * 8];
                Be1 = *(const bf16x8*)&wmT[(tp * 32 + col) * WS + 32 + quad * 8];
                Bo0 = *(const bf16x8*)&wmT[(tp * 32 + 16 + col) * WS + quad * 8];
                Bo1 = *(const bf16x8*)&wmT[(tp * 32 + 16 + col) * WS + 32 + quad * 8];
            }
            f32x4 de = mfma16(am1, Be1, mfma16(am0, Be0, z));
            f32x4 dq = mfma16(am1, Bo1, mfma16(am0, Bo0, z));
            #pragma unroll
            for (int r = 0; r < 4; r++) {       // C rows 0..15 = the wave's 16 points
                int pp = pbase + quad * 4 + r;
                float ye = fmaxf(de[r] * sme[tp] + bme[tp], 0.f);
                float yo = fmaxf(dq[r] * smo[tp] + bmo[tp], 0.f);
                *(unsigned*)&out[(size_t)pp * NOUT + tp * 32 + 2 * col] = pk2(ye, yo);
            }
        }
    }
}

// ---------------------------------------------------------------- kernel 4: out = leaky(cb(f_pc2,mlp2) + cb(feature,sc))
// channel-pair interleaved weights -> float2 stores; scales in registers; no LDS.
__global__ __launch_bounds__(256)
void k_out(const unsigned short* __restrict__ f_pc2, const float* __restrict__ feature,
           const unsigned short* __restrict__ pk,
           const float* __restrict__ s2, const float* __restrict__ b2,
           const float* __restrict__ ssc, const float* __restrict__ bsc,
           float* __restrict__ out)
{
    const int tid = threadIdx.x;
    const int lid = tid & 63, wv = tid >> 6;
    const int col = lid & 15, quad = lid >> 4;
    const unsigned short* w2T = pk + PK_W2;
    const unsigned short* wsT = pk + PK_WS;
    float sse[4], sso[4], ste[4], sto[4], bbe[4], bbo[4];
    #pragma unroll
    for (int m = 0; m < 4; m++) {
        int ce = m * 32 + 2 * col, co = ce + 1;
        sse[m] = s2[ce]; sso[m] = s2[co];
        ste[m] = ssc[ce]; sto[m] = ssc[co];
        bbe[m] = b2[ce] + bsc[ce]; bbo[m] = b2[co] + bsc[co];
    }
    const f32x4 z = {0.f, 0.f, 0.f, 0.f};
    #pragma unroll 1
    for (int itp = 0; itp < 2; itp++) {
        const int p0 = blockIdx.x * 128 + wv * 32 + itp * 16;
        const unsigned short* ar = &f_pc2[(size_t)(p0 + col) * 64 + quad * 8];
        bf16x8 a10 = *(const bf16x8*)ar;
        bf16x8 a11 = *(const bf16x8*)(ar + 32);
        const float* fr = &feature[(size_t)(p0 + col) * 32 + quad * 8];
        float4 u0 = *(const float4*)fr;
        float4 u1 = *(const float4*)(fr + 4);
        bf16x8 a2 = pack8(u0.x, u0.y, u0.z, u0.w, u1.x, u1.y, u1.z, u1.w);
        #pragma unroll
        for (int m = 0; m < 4; m++) {
            bf16x8 ke0 = *(const bf16x8*)&w2T[(m * 32 + col) * 88 + quad * 8];
            bf16x8 ke1 = *(const bf16x8*)&w2T[(m * 32 + col) * 88 + 32 + quad * 8];
            bf16x8 ko0 = *(const bf16x8*)&w2T[(m * 32 + 16 + col) * 88 + quad * 8];
            bf16x8 ko1 = *(const bf16x8*)&w2T[(m * 32 + 16 + col) * 88 + 32 + quad * 8];
            bf16x8 se  = *(const bf16x8*)&wsT[(m * 32 + col) * 40 + quad * 8];
            bf16x8 so  = *(const bf16x8*)&wsT[(m * 32 + 16 + col) * 40 + quad * 8];
            f32x4 de = mfma16(a11, ke1, mfma16(a10, ke0, z));
            f32x4 dq = mfma16(a11, ko1, mfma16(a10, ko0, z));
            f32x4 ee = mfma16(a2, se, z);
            f32x4 eo = mfma16(a2, so, z);
            #pragma unroll
            for (int r = 0; r < 4; r++) {
                float ye = de[r] * sse[m] + ee[r] * ste[m] + bbe[m];
                float yo = dq[r] * sso[m] + eo[r] * sto[m] + bbo[m];
                ye = ye > 0.f ? ye : 0.2f * ye;
                yo = yo > 0.f ? yo : 0.2f * yo;
                *(float2*)&out[(size_t)(p0 + quad * 4 + r) * 128 + m * 32 + 2 * col] =
                    make_float2(ye, yo);
            }
        }
    }
}

// ---------------------------------------------------------------- launch
extern "C" void kernel_launch(void* const* d_in, const int* in_sizes, int n_in,
                              void* d_out, int out_size, void* d_ws, size_t ws_size,
                              hipStream_t stream) {
    const float* feature = (const float*)d_in[0];
    const float* xyz     = (const float*)d_in[1];
    const int*   nidx    = (const int*)d_in[2];
    const float* w_mlp1 = (const float*)d_in[3];
    const float* s_mlp1 = (const float*)d_in[4];
    const float* b_mlp1 = (const float*)d_in[5];
    const float* w_lfa1 = (const float*)d_in[6];
    const float* s_lfa1 = (const float*)d_in[7];
    const float* b_lfa1 = (const float*)d_in[8];
    const float* w_att1_fc  = (const float*)d_in[9];
    const float* w_att1_mlp = (const float*)d_in[10];
    const float* s_att1_mlp = (const float*)d_in[11];
    const float* b_att1_mlp = (const float*)d_in[12];
    const float* w_lfa2 = (const float*)d_in[13];
    const float* s_lfa2 = (const float*)d_in[14];
    const float* b_lfa2 = (const float*)d_in[15];
    const float* w_att2_fc  = (const float*)d_in[16];
    const float* w_att2_mlp = (const float*)d_in[17];
    const float* s_att2_mlp = (const float*)d_in[18];
    const float* b_att2_mlp = (const float*)d_in[19];
    const float* w_mlp2 = (const float*)d_in[20];
    const float* s_mlp2 = (const float*)d_in[21];
    const float* b_mlp2 = (const float*)d_in[22];
    const float* w_sc = (const float*)d_in[23];
    const float* s_sc = (const float*)d_in[24];
    const float* b_sc = (const float*)d_in[25];

    unsigned short* f_pc  = (unsigned short*)d_ws;               // [BNPTS][32] bf16
    unsigned short* f_agg = f_pc  + (size_t)BNPTS * 32;          // [BNPTS][32] bf16
    unsigned short* f_pc2 = f_agg + (size_t)BNPTS * 32;          // [BNPTS][64] bf16
    unsigned short* pkw   = f_pc2 + (size_t)BNPTS * 64;          // packed weights
    float*          xyz4  = (float*)(pkw + PK_TOTAL);            // [BNPTS] float4
    float* out = (float*)d_out;

    k_prep<<<8 + BNPTS / 256, 256, 0, stream>>>(
        w_mlp1, w_att1_fc, w_att2_fc,
        w_lfa1, s_lfa1, b_lfa1, w_lfa2,
        w_att1_mlp, w_att2_mlp, w_mlp2, w_sc, xyz, pkw, xyz4);
    k_mlp1<<<BNPTS / 256, 256, 0, stream>>>(feature, pkw, s_mlp1, b_mlp1, f_pc);
    k_att<32, false><<<BNPTS / 64, 256, 0, stream>>>(
        xyz4, nidx, f_pc,
        pkw + PK_L1, pkw + PK_L1,            // lfa2 slots unused
        s_lfa1, b_lfa1,
        pkw + PK_FC1, pkw + PK_M1, s_att1_mlp, b_att1_mlp, f_agg);
    k_att<64, true><<<BNPTS / 64, 256, 0, stream>>>(
        xyz4, nidx, f_agg,
        pkw + PK_L1, pkw + PK_L2,
        s_lfa2, b_lfa2,
        pkw + PK_FC2, pkw + PK_M2, s_att2_mlp, b_att2_mlp, f_pc2);
    k_out<<<BNPTS / 128, 256, 0, stream>>>(
        f_pc2, feature, pkw,
        s_mlp2, b_mlp2, s_sc, b_sc, out);
}

// Round 10
// 355.487 us; speedup vs baseline: 1.0137x; 1.0137x over previous
//
#include <hip/hip_runtime.h>
#include <hip/hip_bf16.h>

#define NPTS  40960
#define BNPTS 163840   // 4 batches x 40960
#define KNB   16

// packed-weight workspace offsets (in shorts), after f_pc2
#define PK_MLP1 0        // [32][40]  (interleaved slots)
#define PK_FC1  1280     // [64][88]  (log2e folded)
#define PK_FC2  6912     // [64][88]  (log2e folded)
#define PK_L1   12544    // [32][40]  (scale/bias folded, interleaved slots)
#define PK_L2   13824    // [32][40]  (interleaved slots)
#define PK_M1   15104    // [32][88]  (interleaved in 32-ch pairs)
#define PK_M2   17920    // [64][88]
#define PK_W2   23552    // [128][88] (interleaved in 32-ch pairs)
#define PK_WS   34816    // [128][40] (interleaved in 32-ch pairs)
#define PK_TOTAL 39936   // shorts (= 79872 B, 16B-aligned)

using bf16x8 = __attribute__((ext_vector_type(8))) short;
using f32x4  = __attribute__((ext_vector_type(4))) float;

__device__ __forceinline__ unsigned short f2bf(float x) {
    union { float f; unsigned u; } v; v.f = x;
    unsigned r = v.u + 0x7fffu + ((v.u >> 16) & 1u);   // RTNE
    return (unsigned short)(r >> 16);
}
__device__ __forceinline__ float bf2f(unsigned short u) {
    union { unsigned u; float f; } v; v.u = ((unsigned)u) << 16;
    return v.f;
}
__device__ __forceinline__ unsigned pk2(float lo, float hi) {
    union { __hip_bfloat162 h; unsigned u; } v;
    v.h = __float22bfloat162_rn(float2{lo, hi});
    return v.u;
}
__device__ __forceinline__ bf16x8 pack8(float a0, float a1, float a2, float a3,
                                        float a4, float a5, float a6, float a7) {
    union { unsigned u[4]; bf16x8 v; } w;
    w.u[0] = pk2(a0, a1); w.u[1] = pk2(a2, a3);
    w.u[2] = pk2(a4, a5); w.u[3] = pk2(a6, a7);
    return w.v;
}
__device__ __forceinline__ f32x4 mfma16(bf16x8 a, bf16x8 b, f32x4 c) {
    return __builtin_amdgcn_mfma_f32_16x16x32_bf16(a, b, c, 0, 0, 0);
}
// trans ops via builtins: compiler inserts the required trans->VALU wait states
__device__ __forceinline__ float exp2_fast(float x) { return __builtin_amdgcn_exp2f(x); }
__device__ __forceinline__ float rcp_fast(float x)  { return __builtin_amdgcn_rcpf(x); }

// ---------------------------------------------------------------- k_prep: pack weights (once, 8 blocks)
__global__ __launch_bounds__(256)
void k_prep(const float* __restrict__ wm1, const float* __restrict__ wfc1,
            const float* __restrict__ wfc2,
            const float* __restrict__ wlfa1, const float* __restrict__ slfa1, const float* __restrict__ blfa1,
            const float* __restrict__ wlfa2,
            const float* __restrict__ wam1, const float* __restrict__ wam2,
            const float* __restrict__ w2, const float* __restrict__ wsc,
            unsigned short* __restrict__ pk)
{
    const int tid = threadIdx.x, blk = blockIdx.x;
    const float LOG2E = 1.4426950408889634f;
    switch (blk) {
    case 0: // mlp1, even/odd interleaved slots (pk2 stores in k_mlp1)
        for (int t = tid; t < 32 * 32; t += 256) {
            int c = t >> 5, d = t & 31;
            int slot = (d & 1) * 16 + (d >> 1);
            pk[PK_MLP1 + slot * 40 + c] = f2bf(wm1[t]);
        }
        break;
    case 1: // att1 fc, log2e folded
        for (int t = tid; t < 64 * 64; t += 256) {
            int c = t >> 6, d = t & 63;
            pk[PK_FC1 + d * 88 + c] = f2bf(wfc1[t] * LOG2E);
        }
        break;
    case 2: // att2 fc, log2e folded
        for (int t = tid; t < 64 * 64; t += 256) {
            int c = t >> 6, d = t & 63;
            pk[PK_FC2 + d * 88 + c] = f2bf(wfc2[t] * LOG2E);
        }
        break;
    case 3: // lfa1 (s,b folded; bias in K-row 10) + lfa2, even/odd interleaved slots
        for (int t = tid; t < 32 * 32; t += 256) {
            int k = t >> 5, d = t & 31;
            int slot = (d & 1) * 16 + (d >> 1);
            float v1 = k < 10 ? wlfa1[k * 32 + d] * slfa1[d] : (k == 10 ? blfa1[d] : 0.f);
            pk[PK_L1 + slot * 40 + k] = f2bf(v1);
            pk[PK_L2 + slot * 40 + k] = f2bf(wlfa2[k * 32 + d]);
        }
        break;
    case 4: // att1 mlp (NOUT=32), interleaved within 32-ch pair
        for (int t = tid; t < 64 * 32; t += 256) {
            int c = t / 32, d = t % 32;
            int slot = (d & 1) * 16 + (d >> 1);
            pk[PK_M1 + slot * 88 + c] = f2bf(wam1[t]);
        }
        break;
    case 5: // att2 mlp (NOUT=64)
        for (int t = tid; t < 64 * 64; t += 256) {
            int c = t >> 6, d = t & 63;
            int slot = (d >> 5) * 32 + (d & 1) * 16 + ((d & 31) >> 1);
            pk[PK_M2 + slot * 88 + c] = f2bf(wam2[t]);
        }
        break;
    case 6: // mlp2 weights [128][88], interleaved within 32-ch groups (float2 stores in k_out)
        for (int t = tid; t < 64 * 128; t += 256) {
            int c = t >> 7, d = t & 127;
            int slot = (d >> 5) * 32 + (d & 1) * 16 + ((d & 31) >> 1);
            pk[PK_W2 + slot * 88 + c] = f2bf(w2[t]);
        }
        break;
    case 7: // shortcut weights [128][40], same interleave
        for (int t = tid; t < 32 * 128; t += 256) {
            int c = t >> 7, d = t & 127;
            int slot = (d >> 5) * 32 + (d & 1) * 16 + ((d & 31) >> 1);
            pk[PK_WS + slot * 40 + c] = f2bf(wsc[t]);
        }
        break;
    }
}

// ---------------------------------------------------------------- kernel 1: f_pc = cb(feature, mlp1) -> bf16 [pts][32]
// also packs xyz -> float4 (grid = BNPTS/256 matches exactly; k_att runs after)
__global__ __launch_bounds__(256)
void k_mlp1(const float* __restrict__ feature, const unsigned short* __restrict__ pk,
            const float* __restrict__ s, const float* __restrict__ b,
            const float* __restrict__ xyz, float* __restrict__ xyz4,
            unsigned short* __restrict__ f_pc)
{
    const int tid = threadIdx.x;
    { // xyz -> float4 pack (folded from k_prep: saves 640-block dispatch)
        int idx = blockIdx.x * 256 + tid;
        float3 v = *(const float3*)&xyz[(size_t)idx * 3];
        *(float4*)&xyz4[(size_t)idx * 4] = make_float4(v.x, v.y, v.z, 0.f);
    }
    const int lid = tid & 63, wv = tid >> 6;
    const int col = lid & 15, quad = lid >> 4;
    bf16x8 B0 = *(const bf16x8*)&pk[PK_MLP1 + col * 40 + quad * 8];         // even ch 2col
    bf16x8 B1 = *(const bf16x8*)&pk[PK_MLP1 + (16 + col) * 40 + quad * 8];  // odd ch 2col+1
    float s0 = s[2 * col], b0 = b[2 * col], s1 = s[2 * col + 1], b1 = b[2 * col + 1];
    for (int itp = 0; itp < 4; itp++) {
        const int p0 = blockIdx.x * 256 + wv * 64 + itp * 16;
        const float* fr = &feature[(size_t)(p0 + col) * 32 + quad * 8];
        float4 u0 = *(const float4*)fr;
        float4 u1 = *(const float4*)(fr + 4);
        bf16x8 a = pack8(u0.x, u0.y, u0.z, u0.w, u1.x, u1.y, u1.z, u1.w);
        f32x4 z = {0.f, 0.f, 0.f, 0.f};
        f32x4 d0 = mfma16(a, B0, z);
        f32x4 d1 = mfma16(a, B1, z);
        #pragma unroll
        for (int r = 0; r < 4; r++) {
            int p = p0 + quad * 4 + r;
            float ye = fmaxf(d0[r] * s0 + b0, 0.f);
            float yo = fmaxf(d1[r] * s1 + b1, 0.f);
            *(unsigned*)&f_pc[(size_t)p * 32 + 2 * col] = pk2(ye, yo);
        }
    }
}

// ---------------------------------------------------------------- attention kernels
// One wave = 16 points. R6-exact structure (known-good) + s_setprio around MFMA
// clusters (T5: k_att has no loop barriers -> waves at independent phases, the
// regime where setprio measured +4-7% on attn; null only for lockstep GEMM).
template<int NOUT, bool HAS_LFA2>
__global__ __launch_bounds__(256, 4)
void k_att(const float* __restrict__ xyz4, const int* __restrict__ nidx,
           const unsigned short* __restrict__ src,
           const unsigned short* __restrict__ wl1T, const unsigned short* __restrict__ wl2T,
           const float* __restrict__ slfa2, const float* __restrict__ blfa2,
           const unsigned short* __restrict__ wfcT, const unsigned short* __restrict__ wmT,
           const float* __restrict__ smlp, const float* __restrict__ bmlp,
           unsigned short* __restrict__ out)
{
    constexpr int NP = NOUT / 32;
    constexpr int WS = 88;                       // fc row stride in shorts
    __shared__ __align__(16) char smem[23552];
    char* uni = smem;

    const int tid = threadIdx.x;
    const int lid = tid & 63, wv = tid >> 6;
    const int col = lid & 15, quad = lid >> 4;

    // ---- fragments: direct global->reg (L2-resident after first blocks)
    bf16x8 Bfc[4][2];
    #pragma unroll
    for (int nt = 0; nt < 4; nt++)
        #pragma unroll
        for (int ks = 0; ks < 2; ks++)
            Bfc[nt][ks] = *(const bf16x8*)&wfcT[(nt * 16 + col) * WS + ks * 32 + quad * 8];
    bf16x8 Bl1e = *(const bf16x8*)&wl1T[col * 40 + quad * 8];
    bf16x8 Bl1o = *(const bf16x8*)&wl1T[(16 + col) * 40 + quad * 8];
    bf16x8 Bl2e{}, Bl2o{};
    float sl2e = 0.f, bl2e = 0.f, sl2o = 0.f, bl2o = 0.f;
    if (HAS_LFA2) {
        Bl2e = *(const bf16x8*)&wl2T[col * 40 + quad * 8];
        Bl2o = *(const bf16x8*)&wl2T[(16 + col) * 40 + quad * 8];
        sl2e = slfa2[2 * col]; bl2e = blfa2[2 * col];
        sl2o = slfa2[2 * col + 1]; bl2o = blfa2[2 * col + 1];
    }
    float sme[NP], bme[NP], smo[NP], bmo[NP];
    #pragma unroll
    for (int tp = 0; tp < NP; tp++) {
        sme[tp] = smlp[tp * 32 + 2 * col]; bme[tp] = bmlp[tp * 32 + 2 * col];
        smo[tp] = smlp[tp * 32 + 2 * col + 1]; bmo[tp] = bmlp[tp * 32 + 2 * col + 1];
    }

    // per-wave loop scratch (wave-private: no block barriers anywhere)
    unsigned short* fc  = (unsigned short*)(uni) + wv * 1408;         // [16 nbr][88]
    unsigned short* ag  = (unsigned short*)(uni + 11264) + wv * 1152; // [16 pts][72]
    unsigned short* nb  = (unsigned short*)(uni + 20480) + wv * 256;  // 16 it x 16 nbr idx (u16)
    float*          cxy = (float*)(uni + 22528) + wv * 64;            // 16 centers x float4

    const int blk = (int)blockIdx.x;
    const int vblk = (blk & 7) * 320 + (blk >> 3);    // XCD swizzle (grid 2560 = 8 x 320)
    const int pbase = vblk * 64 + wv * 16;
    const int pb = (pbase / NPTS) * NPTS;
    const unsigned short* srcb = src + (size_t)pb * 32;
    const float4* x4  = (const float4*)xyz4;
    const float4* x4b = x4 + pb;

    { // stage this wave's 256 neighbor indices (N=40960 fits u16) + 16 center float4s
        int4 t4 = *(const int4*)&nidx[(size_t)pbase * KNB + lid * 4];
        ushort4 u = make_ushort4((unsigned short)t4.x, (unsigned short)t4.y,
                                 (unsigned short)t4.z, (unsigned short)t4.w);
        *(ushort4*)&nb[lid * 4] = u;
        if (lid < 16) *(float4*)&cxy[lid * 4] = x4[pbase + lid];
    }

    const f32x4 z = {0.f, 0.f, 0.f, 0.f};
    bf16x8 vs; float nx = 0.f, ny = 0.f, nz = 0.f;
    { // prefetch iteration 0
        int j = (int)nb[col];
        vs = *(const bf16x8*)(srcb + (size_t)j * 32 + quad * 8);
        if (quad < 2) { float4 t = x4b[j]; nx = t.x; ny = t.y; nz = t.z; }
    }

    #pragma unroll 1
    for (int it = 0; it < 16; it++) {
        bf16x8 a0 = vs;                                 // gathered nbr feats: rows=col, k=quad*8..
        *(bf16x8*)&fc[col * WS + quad * 8] = a0;        // LDS copy only for softmax-weighted sum

        // rel_pos from prefetched neighbor xyz + staged center xyz
        float cx = cxy[it * 4], cy = cxy[it * 4 + 1], cz = cxy[it * 4 + 2];
        float rx = cx - nx, ry = cy - ny, rz = cz - nz;
        float dd = sqrtf(rx * rx + ry * ry + rz * rz);
        float f0 = 0.f, f1 = 0.f, f2 = 0.f, f3 = 0.f, f4 = 0.f, f5 = 0.f, f6 = 0.f, f7 = 0.f;
        if (quad == 0)      { f0 = dd; f1 = rx; f2 = ry; f3 = rz; f4 = cx; f5 = cy; f6 = cz; f7 = nx; }
        else if (quad == 1) { f0 = ny; f1 = nz; f2 = 1.0f; }   // k=10: folded lfa1 bias row
        bf16x8 al = pack8(f0, f1, f2, f3, f4, f5, f6, f7);

        { // prefetch next iteration (clamped; last iter redoes it=15, harmless)
            int itn = it < 15 ? it + 1 : 15;
            int j = (int)nb[itn * 16 + col];
            vs = *(const bf16x8*)(srcb + (size_t)j * 32 + quad * 8);
            if (quad < 2) { float4 t = x4b[j]; nx = t.x; ny = t.y; nz = t.z; }
        }

        { // ---- lfa1 (+ lfa2) -> fc[:, 32:64]   [MFMA cluster: boost prio]
            __builtin_amdgcn_s_setprio(1);
            f32x4 d0 = mfma16(al, Bl1e, z);
            f32x4 d1 = mfma16(al, Bl1o, z);
            __builtin_amdgcn_s_setprio(0);
            #pragma unroll
            for (int r = 0; r < 4; r++) {
                float ye = fmaxf(d0[r], 0.f);            // scale/bias folded into W
                float yo = fmaxf(d1[r], 0.f);
                *(unsigned*)&fc[(quad * 4 + r) * WS + 32 + 2 * col] = pk2(ye, yo);
            }
            if (HAS_LFA2) {
                bf16x8 a2 = *(const bf16x8*)&fc[col * WS + 32 + quad * 8];
                __builtin_amdgcn_s_setprio(1);
                f32x4 e0 = mfma16(a2, Bl2e, z);
                f32x4 e1 = mfma16(a2, Bl2o, z);
                __builtin_amdgcn_s_setprio(0);
                #pragma unroll
                for (int r = 0; r < 4; r++) {
                    float ye = fmaxf(e0[r] * sl2e + bl2e, 0.f);
                    float yo = fmaxf(e1[r] * sl2o + bl2o, 0.f);
                    *(unsigned*)&fc[(quad * 4 + r) * WS + 32 + 2 * col] = pk2(ye, yo);
                }
            }
        }

        { // ---- logits GEMM (log2e pre-folded) + softmax over 16 nbrs + pooled agg
            bf16x8 a1 = *(const bf16x8*)&fc[col * WS + 32 + quad * 8];
            #pragma unroll
            for (int nt = 0; nt < 4; nt++) {
                __builtin_amdgcn_s_setprio(1);
                f32x4 L = mfma16(a1, Bfc[nt][1], mfma16(a0, Bfc[nt][0], z));
                __builtin_amdgcn_s_setprio(0);
                float e0 = exp2_fast(L[0]), e1 = exp2_fast(L[1]);
                float e2 = exp2_fast(L[2]), e3 = exp2_fast(L[3]);
                float sden = (e0 + e1) + (e2 + e3);
                const unsigned short* frr = &fc[quad * 4 * WS + nt * 16 + col];
                float av = e0 * bf2f(frr[0]) + e1 * bf2f(frr[WS]) + e2 * bf2f(frr[2 * WS]) + e3 * bf2f(frr[3 * WS]);
                av   += __shfl_xor(av, 16, 64);
                sden += __shfl_xor(sden, 16, 64);
                av   += __shfl_xor(av, 32, 64);
                sden += __shfl_xor(sden, 32, 64);
                if (quad == 0) ag[it * 72 + nt * 16 + col] = f2bf(av * rcp_fast(sden));
            }
        }
    }

    // ---- att-MLP batched over the wave's 16 points (full 16-row MFMA)
    {
        bf16x8 am0 = *(const bf16x8*)&ag[col * 72 + quad * 8];
        bf16x8 am1 = *(const bf16x8*)&ag[col * 72 + 32 + quad * 8];
        #pragma unroll
        for (int tp = 0; tp < NP; tp++) {
            bf16x8 Be0, Be1, Bo0, Bo1;
            if constexpr (NOUT == 32) {
                Be0 = *(const bf16x8*)&wmT[col * WS + quad * 8];
                Be1 = *(const bf16x8*)&wmT[col * WS + 32 + quad * 8];
                Bo0 = *(const bf16x8*)&wmT[(16 + col) * WS + quad * 8];
                Bo1 = *(const bf16x8*)&wmT[(16 + col) * WS + 32 + quad * 8];
            } else {
                Be0 = *(const bf16x8*)&wmT[(tp * 32 + col) * WS + quad * 8];
                Be1 = *(const bf16x8*)&wmT[(tp * 32 + col) * WS + 32 + quad * 8];
                Bo0 = *(const bf16x8*)&wmT[(tp * 32 + 16 + col) * WS + quad * 8];
                Bo1 = *(const bf16x8*)&wmT[(tp * 32 + 16 + col) * WS + 32 + quad * 8];
            }
            __builtin_amdgcn_s_setprio(1);
            f32x4 de = mfma16(am1, Be1, mfma16(am0, Be0, z));
            f32x4 dq = mfma16(am1, Bo1, mfma16(am0, Bo0, z));
            __builtin_amdgcn_s_setprio(0);
            #pragma unroll
            for (int r = 0; r < 4; r++) {       // C rows 0..15 = the wave's 16 points
                int pp = pbase + quad * 4 + r;
                float ye = fmaxf(de[r] * sme[tp] + bme[tp], 0.f);
                float yo = fmaxf(dq[r] * smo[tp] + bmo[tp], 0.f);
                *(unsigned*)&out[(size_t)pp * NOUT + tp * 32 + 2 * col] = pk2(ye, yo);
            }
        }
    }
}

// ---------------------------------------------------------------- kernel 4: out = leaky(cb(f_pc2,mlp2) + cb(feature,sc))
// channel-pair interleaved weights -> float2 stores; scales in registers; no LDS.
__global__ __launch_bounds__(256)
void k_out(const unsigned short* __restrict__ f_pc2, const float* __restrict__ feature,
           const unsigned short* __restrict__ pk,
           const float* __restrict__ s2, const float* __restrict__ b2,
           const float* __restrict__ ssc, const float* __restrict__ bsc,
           float* __restrict__ out)
{
    const int tid = threadIdx.x;
    const int lid = tid & 63, wv = tid >> 6;
    const int col = lid & 15, quad = lid >> 4;
    const unsigned short* w2T = pk + PK_W2;
    const unsigned short* wsT = pk + PK_WS;
    float sse[4], sso[4], ste[4], sto[4], bbe[4], bbo[4];
    #pragma unroll
    for (int m = 0; m < 4; m++) {
        int ce = m * 32 + 2 * col, co = ce + 1;
        sse[m] = s2[ce]; sso[m] = s2[co];
        ste[m] = ssc[ce]; sto[m] = ssc[co];
        bbe[m] = b2[ce] + bsc[ce]; bbo[m] = b2[co] + bsc[co];
    }
    const f32x4 z = {0.f, 0.f, 0.f, 0.f};
    #pragma unroll 1
    for (int itp = 0; itp < 2; itp++) {
        const int p0 = blockIdx.x * 128 + wv * 32 + itp * 16;
        const unsigned short* ar = &f_pc2[(size_t)(p0 + col) * 64 + quad * 8];
        bf16x8 a10 = *(const bf16x8*)ar;
        bf16x8 a11 = *(const bf16x8*)(ar + 32);
        const float* fr = &feature[(size_t)(p0 + col) * 32 + quad * 8];
        float4 u0 = *(const float4*)fr;
        float4 u1 = *(const float4*)(fr + 4);
        bf16x8 a2 = pack8(u0.x, u0.y, u0.z, u0.w, u1.x, u1.y, u1.z, u1.w);
        #pragma unroll
        for (int m = 0; m < 4; m++) {
            bf16x8 ke0 = *(const bf16x8*)&w2T[(m * 32 + col) * 88 + quad * 8];
            bf16x8 ke1 = *(const bf16x8*)&w2T[(m * 32 + col) * 88 + 32 + quad * 8];
            bf16x8 ko0 = *(const bf16x8*)&w2T[(m * 32 + 16 + col) * 88 + quad * 8];
            bf16x8 ko1 = *(const bf16x8*)&w2T[(m * 32 + 16 + col) * 88 + 32 + quad * 8];
            bf16x8 se  = *(const bf16x8*)&wsT[(m * 32 + col) * 40 + quad * 8];
            bf16x8 so  = *(const bf16x8*)&wsT[(m * 32 + 16 + col) * 40 + quad * 8];
            f32x4 de = mfma16(a11, ke1, mfma16(a10, ke0, z));
            f32x4 dq = mfma16(a11, ko1, mfma16(a10, ko0, z));
            f32x4 ee = mfma16(a2, se, z);
            f32x4 eo = mfma16(a2, so, z);
            #pragma unroll
            for (int r = 0; r < 4; r++) {
                float ye = de[r] * sse[m] + ee[r] * ste[m] + bbe[m];
                float yo = dq[r] * sso[m] + eo[r] * sto[m] + bbo[m];
                ye = ye > 0.f ? ye : 0.2f * ye;
                yo = yo > 0.f ? yo : 0.2f * yo;
                *(float2*)&out[(size_t)(p0 + quad * 4 + r) * 128 + m * 32 + 2 * col] =
                    make_float2(ye, yo);
            }
        }
    }
}

// ---------------------------------------------------------------- launch
extern "C" void kernel_launch(void* const* d_in, const int* in_sizes, int n_in,
                              void* d_out, int out_size, void* d_ws, size_t ws_size,
                              hipStream_t stream) {
    const float* feature = (const float*)d_in[0];
    const float* xyz     = (const float*)d_in[1];
    const int*   nidx    = (const int*)d_in[2];
    const float* w_mlp1 = (const float*)d_in[3];
    const float* s_mlp1 = (const float*)d_in[4];
    const float* b_mlp1 = (const float*)d_in[5];
    const float* w_lfa1 = (const float*)d_in[6];
    const float* s_lfa1 = (const float*)d_in[7];
    const float* b_lfa1 = (const float*)d_in[8];
    const float* w_att1_fc  = (const float*)d_in[9];
    const float* w_att1_mlp = (const float*)d_in[10];
    const float* s_att1_mlp = (const float*)d_in[11];
    const float* b_att1_mlp = (const float*)d_in[12];
    const float* w_lfa2 = (const float*)d_in[13];
    const float* s_lfa2 = (const float*)d_in[14];
    const float* b_lfa2 = (const float*)d_in[15];
    const float* w_att2_fc  = (const float*)d_in[16];
    const float* w_att2_mlp = (const float*)d_in[17];
    const float* s_att2_mlp = (const float*)d_in[18];
    const float* b_att2_mlp = (const float*)d_in[19];
    const float* w_mlp2 = (const float*)d_in[20];
    const float* s_mlp2 = (const float*)d_in[21];
    const float* b_mlp2 = (const float*)d_in[22];
    const float* w_sc = (const float*)d_in[23];
    const float* s_sc = (const float*)d_in[24];
    const float* b_sc = (const float*)d_in[25];

    unsigned short* f_pc  = (unsigned short*)d_ws;               // [BNPTS][32] bf16
    unsigned short* f_agg = f_pc  + (size_t)BNPTS * 32;          // [BNPTS][32] bf16
    unsigned short* f_pc2 = f_agg + (size_t)BNPTS * 32;          // [BNPTS][64] bf16
    unsigned short* pkw   = f_pc2 + (size_t)BNPTS * 64;          // packed weights
    float*          xyz4  = (float*)(pkw + PK_TOTAL);            // [BNPTS] float4
    float* out = (float*)d_out;

    k_prep<<<8, 256, 0, stream>>>(
        w_mlp1, w_att1_fc, w_att2_fc,
        w_lfa1, s_lfa1, b_lfa1, w_lfa2,
        w_att1_mlp, w_att2_mlp, w_mlp2, w_sc, pkw);
    k_mlp1<<<BNPTS / 256, 256, 0, stream>>>(feature, pkw, s_mlp1, b_mlp1, xyz, xyz4, f_pc);
    k_att<32, false><<<BNPTS / 64, 256, 0, stream>>>(
        xyz4, nidx, f_pc,
        pkw + PK_L1, pkw + PK_L1,            // lfa2 slots unused
        s_lfa1, b_lfa1,
        pkw + PK_FC1, pkw + PK_M1, s_att1_mlp, b_att1_mlp, f_agg);
    k_att<64, true><<<BNPTS / 64, 256, 0, stream>>>(
        xyz4, nidx, f_agg,
        pkw + PK_L1, pkw + PK_L2,
        s_lfa2, b_lfa2,
        pkw + PK_FC2, pkw + PK_M2, s_att2_mlp, b_att2_mlp, f_pc2);
    k_out<<<BNPTS / 128, 256, 0, stream>>>(
        f_pc2, feature, pkw,
        s_mlp2, b_mlp2, s_sc, b_sc, out);
}

// Round 11
// 337.344 us; speedup vs baseline: 1.0682x; 1.0538x over previous
//
#include <hip/hip_runtime.h>
#include <hip/hip_bf16.h>

#define NPTS  40960
#define BNPTS 163840   // 4 batches x 40960
#define KNB   16

// packed-weight workspace offsets (in shorts), after f_pc2
#define PK_MLP1 0        // [32][40]  (interleaved slots)
#define PK_FC1  1280     // [64][88]  (log2e folded)
#define PK_FC2  6912     // [64][88]  (log2e folded)
#define PK_L1   12544    // [32][40]  (scale/bias folded, interleaved slots)
#define PK_L2   13824    // [32][40]  (interleaved slots)
#define PK_M1   15104    // [32][88]  (interleaved in 32-ch pairs)
#define PK_M2   17920    // [64][88]
#define PK_W2   23552    // [128][88] (interleaved in 32-ch pairs)
#define PK_WS   34816    // [128][40] (interleaved in 32-ch pairs)
#define PK_TOTAL 39936   // shorts (= 79872 B, 16B-aligned)

using bf16x8 = __attribute__((ext_vector_type(8))) short;
using f32x4  = __attribute__((ext_vector_type(4))) float;

__device__ __forceinline__ unsigned short f2bf(float x) {
    union { float f; unsigned u; } v; v.f = x;
    unsigned r = v.u + 0x7fffu + ((v.u >> 16) & 1u);   // RTNE
    return (unsigned short)(r >> 16);
}
__device__ __forceinline__ float bf2f(unsigned short u) {
    union { unsigned u; float f; } v; v.u = ((unsigned)u) << 16;
    return v.f;
}
__device__ __forceinline__ unsigned pk2(float lo, float hi) {
    union { __hip_bfloat162 h; unsigned u; } v;
    v.h = __float22bfloat162_rn(float2{lo, hi});
    return v.u;
}
__device__ __forceinline__ bf16x8 pack8(float a0, float a1, float a2, float a3,
                                        float a4, float a5, float a6, float a7) {
    union { unsigned u[4]; bf16x8 v; } w;
    w.u[0] = pk2(a0, a1); w.u[1] = pk2(a2, a3);
    w.u[2] = pk2(a4, a5); w.u[3] = pk2(a6, a7);
    return w.v;
}
__device__ __forceinline__ f32x4 mfma16(bf16x8 a, bf16x8 b, f32x4 c) {
    return __builtin_amdgcn_mfma_f32_16x16x32_bf16(a, b, c, 0, 0, 0);
}
// trans ops via builtins: compiler inserts the required trans->VALU wait states
__device__ __forceinline__ float exp2_fast(float x) { return __builtin_amdgcn_exp2f(x); }
__device__ __forceinline__ float rcp_fast(float x)  { return __builtin_amdgcn_rcpf(x); }

// ---------------------------------------------------------------- k_prep: pack weights (once, 8 blocks)
__global__ __launch_bounds__(256)
void k_prep(const float* __restrict__ wm1, const float* __restrict__ wfc1,
            const float* __restrict__ wfc2,
            const float* __restrict__ wlfa1, const float* __restrict__ slfa1, const float* __restrict__ blfa1,
            const float* __restrict__ wlfa2,
            const float* __restrict__ wam1, const float* __restrict__ wam2,
            const float* __restrict__ w2, const float* __restrict__ wsc,
            unsigned short* __restrict__ pk)
{
    const int tid = threadIdx.x, blk = blockIdx.x;
    const float LOG2E = 1.4426950408889634f;
    switch (blk) {
    case 0: // mlp1, even/odd interleaved slots (pk2 stores in k_mlp1)
        for (int t = tid; t < 32 * 32; t += 256) {
            int c = t >> 5, d = t & 31;
            int slot = (d & 1) * 16 + (d >> 1);
            pk[PK_MLP1 + slot * 40 + c] = f2bf(wm1[t]);
        }
        break;
    case 1: // att1 fc, log2e folded
        for (int t = tid; t < 64 * 64; t += 256) {
            int c = t >> 6, d = t & 63;
            pk[PK_FC1 + d * 88 + c] = f2bf(wfc1[t] * LOG2E);
        }
        break;
    case 2: // att2 fc, log2e folded
        for (int t = tid; t < 64 * 64; t += 256) {
            int c = t >> 6, d = t & 63;
            pk[PK_FC2 + d * 88 + c] = f2bf(wfc2[t] * LOG2E);
        }
        break;
    case 3: // lfa1 (s,b folded; bias in K-row 10) + lfa2, even/odd interleaved slots
        for (int t = tid; t < 32 * 32; t += 256) {
            int k = t >> 5, d = t & 31;
            int slot = (d & 1) * 16 + (d >> 1);
            float v1 = k < 10 ? wlfa1[k * 32 + d] * slfa1[d] : (k == 10 ? blfa1[d] : 0.f);
            pk[PK_L1 + slot * 40 + k] = f2bf(v1);
            pk[PK_L2 + slot * 40 + k] = f2bf(wlfa2[k * 32 + d]);
        }
        break;
    case 4: // att1 mlp (NOUT=32), interleaved within 32-ch pair
        for (int t = tid; t < 64 * 32; t += 256) {
            int c = t / 32, d = t % 32;
            int slot = (d & 1) * 16 + (d >> 1);
            pk[PK_M1 + slot * 88 + c] = f2bf(wam1[t]);
        }
        break;
    case 5: // att2 mlp (NOUT=64)
        for (int t = tid; t < 64 * 64; t += 256) {
            int c = t >> 6, d = t & 63;
            int slot = (d >> 5) * 32 + (d & 1) * 16 + ((d & 31) >> 1);
            pk[PK_M2 + slot * 88 + c] = f2bf(wam2[t]);
        }
        break;
    case 6: // mlp2 weights [128][88], interleaved within 32-ch groups (float2 stores in fused tail)
        for (int t = tid; t < 64 * 128; t += 256) {
            int c = t >> 7, d = t & 127;
            int slot = (d >> 5) * 32 + (d & 1) * 16 + ((d & 31) >> 1);
            pk[PK_W2 + slot * 88 + c] = f2bf(w2[t]);
        }
        break;
    case 7: // shortcut weights [128][40], same interleave
        for (int t = tid; t < 32 * 128; t += 256) {
            int c = t >> 7, d = t & 127;
            int slot = (d >> 5) * 32 + (d & 1) * 16 + ((d & 31) >> 1);
            pk[PK_WS + slot * 40 + c] = f2bf(wsc[t]);
        }
        break;
    }
}

// ---------------------------------------------------------------- kernel 1: f_pc = cb(feature, mlp1) -> bf16 [pts][32]
// also packs xyz -> float4 (grid = BNPTS/256 matches exactly; k_att runs after)
__global__ __launch_bounds__(256)
void k_mlp1(const float* __restrict__ feature, const unsigned short* __restrict__ pk,
            const float* __restrict__ s, const float* __restrict__ b,
            const float* __restrict__ xyz, float* __restrict__ xyz4,
            unsigned short* __restrict__ f_pc)
{
    const int tid = threadIdx.x;
    { // xyz -> float4 pack (folded from k_prep: saves 640-block dispatch)
        int idx = blockIdx.x * 256 + tid;
        float3 v = *(const float3*)&xyz[(size_t)idx * 3];
        *(float4*)&xyz4[(size_t)idx * 4] = make_float4(v.x, v.y, v.z, 0.f);
    }
    const int lid = tid & 63, wv = tid >> 6;
    const int col = lid & 15, quad = lid >> 4;
    bf16x8 B0 = *(const bf16x8*)&pk[PK_MLP1 + col * 40 + quad * 8];         // even ch 2col
    bf16x8 B1 = *(const bf16x8*)&pk[PK_MLP1 + (16 + col) * 40 + quad * 8];  // odd ch 2col+1
    float s0 = s[2 * col], b0 = b[2 * col], s1 = s[2 * col + 1], b1 = b[2 * col + 1];
    for (int itp = 0; itp < 4; itp++) {
        const int p0 = blockIdx.x * 256 + wv * 64 + itp * 16;
        const float* fr = &feature[(size_t)(p0 + col) * 32 + quad * 8];
        float4 u0 = *(const float4*)fr;
        float4 u1 = *(const float4*)(fr + 4);
        bf16x8 a = pack8(u0.x, u0.y, u0.z, u0.w, u1.x, u1.y, u1.z, u1.w);
        f32x4 z = {0.f, 0.f, 0.f, 0.f};
        f32x4 d0 = mfma16(a, B0, z);
        f32x4 d1 = mfma16(a, B1, z);
        #pragma unroll
        for (int r = 0; r < 4; r++) {
            int p = p0 + quad * 4 + r;
            float ye = fmaxf(d0[r] * s0 + b0, 0.f);
            float yo = fmaxf(d1[r] * s1 + b1, 0.f);
            *(unsigned*)&f_pc[(size_t)p * 32 + 2 * col] = pk2(ye, yo);
        }
    }
}

// ---------------------------------------------------------------- attention kernels
// One wave = 16 points. R6-exact loop (setprio removed: R10 measured neutral).
// NOUT==64: k_out FUSED into the tail. The att-MLP already holds all f_pc2
// values in registers; they go to a wave-private LDS buffer fp2[16][72]
// (72-stride -> 2-way bank conflict = free), then the verbatim k_out epilogue
// (mlp2 + shortcut + leaky) runs in-wave. No barrier (wave-private), deletes
// the k_out dispatch + 42 MB f_pc2 round-trip.
template<int NOUT, bool HAS_LFA2>
__global__ __launch_bounds__(256, 4)
void k_att(const float* __restrict__ xyz4, const int* __restrict__ nidx,
           const unsigned short* __restrict__ src,
           const unsigned short* __restrict__ wl1T, const unsigned short* __restrict__ wl2T,
           const float* __restrict__ slfa2, const float* __restrict__ blfa2,
           const unsigned short* __restrict__ wfcT, const unsigned short* __restrict__ wmT,
           const float* __restrict__ smlp, const float* __restrict__ bmlp,
           unsigned short* __restrict__ out,
           const float* __restrict__ feature,
           const unsigned short* __restrict__ w2T, const unsigned short* __restrict__ wsT,
           const float* __restrict__ s2, const float* __restrict__ b2,
           const float* __restrict__ ssc, const float* __restrict__ bsc,
           float* __restrict__ outF)
{
    constexpr int NP = NOUT / 32;
    constexpr int WS = 88;                       // fc row stride in shorts
    __shared__ __align__(16) char smem[23552];
    __shared__ __align__(16) unsigned short fp2_s[NOUT == 64 ? 4 * 1152 : 8];  // [wv][16][72]
    char* uni = smem;

    const int tid = threadIdx.x;
    const int lid = tid & 63, wv = tid >> 6;
    const int col = lid & 15, quad = lid >> 4;

    // ---- fragments: direct global->reg (L2-resident after first blocks)
    bf16x8 Bfc[4][2];
    #pragma unroll
    for (int nt = 0; nt < 4; nt++)
        #pragma unroll
        for (int ks = 0; ks < 2; ks++)
            Bfc[nt][ks] = *(const bf16x8*)&wfcT[(nt * 16 + col) * WS + ks * 32 + quad * 8];
    bf16x8 Bl1e = *(const bf16x8*)&wl1T[col * 40 + quad * 8];
    bf16x8 Bl1o = *(const bf16x8*)&wl1T[(16 + col) * 40 + quad * 8];
    bf16x8 Bl2e{}, Bl2o{};
    float sl2e = 0.f, bl2e = 0.f, sl2o = 0.f, bl2o = 0.f;
    if (HAS_LFA2) {
        Bl2e = *(const bf16x8*)&wl2T[col * 40 + quad * 8];
        Bl2o = *(const bf16x8*)&wl2T[(16 + col) * 40 + quad * 8];
        sl2e = slfa2[2 * col]; bl2e = blfa2[2 * col];
        sl2o = slfa2[2 * col + 1]; bl2o = blfa2[2 * col + 1];
    }
    float sme[NP], bme[NP], smo[NP], bmo[NP];
    #pragma unroll
    for (int tp = 0; tp < NP; tp++) {
        sme[tp] = smlp[tp * 32 + 2 * col]; bme[tp] = bmlp[tp * 32 + 2 * col];
        smo[tp] = smlp[tp * 32 + 2 * col + 1]; bmo[tp] = bmlp[tp * 32 + 2 * col + 1];
    }

    // per-wave loop scratch (wave-private: no block barriers anywhere)
    unsigned short* fc  = (unsigned short*)(uni) + wv * 1408;         // [16 nbr][88]
    unsigned short* ag  = (unsigned short*)(uni + 11264) + wv * 1152; // [16 pts][72]
    unsigned short* nb  = (unsigned short*)(uni + 20480) + wv * 256;  // 16 it x 16 nbr idx (u16)
    float*          cxy = (float*)(uni + 22528) + wv * 64;            // 16 centers x float4
    unsigned short* fp2 = fp2_s + wv * 1152;                          // [16 pts][72] (NOUT==64)

    const int blk = (int)blockIdx.x;
    const int vblk = (blk & 7) * 320 + (blk >> 3);    // XCD swizzle (grid 2560 = 8 x 320)
    const int pbase = vblk * 64 + wv * 16;
    const int pb = (pbase / NPTS) * NPTS;
    const unsigned short* srcb = src + (size_t)pb * 32;
    const float4* x4  = (const float4*)xyz4;
    const float4* x4b = x4 + pb;

    { // stage this wave's 256 neighbor indices (N=40960 fits u16) + 16 center float4s
        int4 t4 = *(const int4*)&nidx[(size_t)pbase * KNB + lid * 4];
        ushort4 u = make_ushort4((unsigned short)t4.x, (unsigned short)t4.y,
                                 (unsigned short)t4.z, (unsigned short)t4.w);
        *(ushort4*)&nb[lid * 4] = u;
        if (lid < 16) *(float4*)&cxy[lid * 4] = x4[pbase + lid];
    }

    const f32x4 z = {0.f, 0.f, 0.f, 0.f};
    bf16x8 vs; float nx = 0.f, ny = 0.f, nz = 0.f;
    { // prefetch iteration 0
        int j = (int)nb[col];
        vs = *(const bf16x8*)(srcb + (size_t)j * 32 + quad * 8);
        if (quad < 2) { float4 t = x4b[j]; nx = t.x; ny = t.y; nz = t.z; }
    }

    #pragma unroll 1
    for (int it = 0; it < 16; it++) {
        bf16x8 a0 = vs;                                 // gathered nbr feats: rows=col, k=quad*8..
        *(bf16x8*)&fc[col * WS + quad * 8] = a0;        // LDS copy only for softmax-weighted sum

        // rel_pos from prefetched neighbor xyz + staged center xyz
        float cx = cxy[it * 4], cy = cxy[it * 4 + 1], cz = cxy[it * 4 + 2];
        float rx = cx - nx, ry = cy - ny, rz = cz - nz;
        float dd = sqrtf(rx * rx + ry * ry + rz * rz);
        float f0 = 0.f, f1 = 0.f, f2 = 0.f, f3 = 0.f, f4 = 0.f, f5 = 0.f, f6 = 0.f, f7 = 0.f;
        if (quad == 0)      { f0 = dd; f1 = rx; f2 = ry; f3 = rz; f4 = cx; f5 = cy; f6 = cz; f7 = nx; }
        else if (quad == 1) { f0 = ny; f1 = nz; f2 = 1.0f; }   // k=10: folded lfa1 bias row
        bf16x8 al = pack8(f0, f1, f2, f3, f4, f5, f6, f7);

        { // prefetch next iteration (clamped; last iter redoes it=15, harmless)
            int itn = it < 15 ? it + 1 : 15;
            int j = (int)nb[itn * 16 + col];
            vs = *(const bf16x8*)(srcb + (size_t)j * 32 + quad * 8);
            if (quad < 2) { float4 t = x4b[j]; nx = t.x; ny = t.y; nz = t.z; }
        }

        { // ---- lfa1 (+ lfa2) -> fc[:, 32:64]
            f32x4 d0 = mfma16(al, Bl1e, z);
            f32x4 d1 = mfma16(al, Bl1o, z);
            #pragma unroll
            for (int r = 0; r < 4; r++) {
                float ye = fmaxf(d0[r], 0.f);            // scale/bias folded into W
                float yo = fmaxf(d1[r], 0.f);
                *(unsigned*)&fc[(quad * 4 + r) * WS + 32 + 2 * col] = pk2(ye, yo);
            }
            if (HAS_LFA2) {
                bf16x8 a2 = *(const bf16x8*)&fc[col * WS + 32 + quad * 8];
                f32x4 e0 = mfma16(a2, Bl2e, z);
                f32x4 e1 = mfma16(a2, Bl2o, z);
                #pragma unroll
                for (int r = 0; r < 4; r++) {
                    float ye = fmaxf(e0[r] * sl2e + bl2e, 0.f);
                    float yo = fmaxf(e1[r] * sl2o + bl2o, 0.f);
                    *(unsigned*)&fc[(quad * 4 + r) * WS + 32 + 2 * col] = pk2(ye, yo);
                }
            }
        }

        { // ---- logits GEMM (log2e pre-folded) + softmax over 16 nbrs + pooled agg
            bf16x8 a1 = *(const bf16x8*)&fc[col * WS + 32 + quad * 8];
            #pragma unroll
            for (int nt = 0; nt < 4; nt++) {
                f32x4 L = mfma16(a1, Bfc[nt][1], mfma16(a0, Bfc[nt][0], z));
                float e0 = exp2_fast(L[0]), e1 = exp2_fast(L[1]);
                float e2 = exp2_fast(L[2]), e3 = exp2_fast(L[3]);
                float sden = (e0 + e1) + (e2 + e3);
                const unsigned short* frr = &fc[quad * 4 * WS + nt * 16 + col];
                float av = e0 * bf2f(frr[0]) + e1 * bf2f(frr[WS]) + e2 * bf2f(frr[2 * WS]) + e3 * bf2f(frr[3 * WS]);
                av   += __shfl_xor(av, 16, 64);
                sden += __shfl_xor(sden, 16, 64);
                av   += __shfl_xor(av, 32, 64);
                sden += __shfl_xor(sden, 32, 64);
                if (quad == 0) ag[it * 72 + nt * 16 + col] = f2bf(av * rcp_fast(sden));
            }
        }
    }

    // ---- att-MLP batched over the wave's 16 points (full 16-row MFMA)
    {
        bf16x8 am0 = *(const bf16x8*)&ag[col * 72 + quad * 8];
        bf16x8 am1 = *(const bf16x8*)&ag[col * 72 + 32 + quad * 8];
        #pragma unroll
        for (int tp = 0; tp < NP; tp++) {
            bf16x8 Be0, Be1, Bo0, Bo1;
            if constexpr (NOUT == 32) {
                Be0 = *(const bf16x8*)&wmT[col * WS + quad * 8];
                Be1 = *(const bf16x8*)&wmT[col * WS + 32 + quad * 8];
                Bo0 = *(const bf16x8*)&wmT[(16 + col) * WS + quad * 8];
                Bo1 = *(const bf16x8*)&wmT[(16 + col) * WS + 32 + quad * 8];
            } else {
                Be0 = *(const bf16x8*)&wmT[(tp * 32 + col) * WS + quad * 8];
                Be1 = *(const bf16x8*)&wmT[(tp * 32 + col) * WS + 32 + quad * 8];
                Bo0 = *(const bf16x8*)&wmT[(tp * 32 + 16 + col) * WS + quad * 8];
                Bo1 = *(const bf16x8*)&wmT[(tp * 32 + 16 + col) * WS + 32 + quad * 8];
            }
            f32x4 de = mfma16(am1, Be1, mfma16(am0, Be0, z));
            f32x4 dq = mfma16(am1, Bo1, mfma16(am0, Bo0, z));
            #pragma unroll
            for (int r = 0; r < 4; r++) {       // C rows 0..15 = the wave's 16 points
                float ye = fmaxf(de[r] * sme[tp] + bme[tp], 0.f);
                float yo = fmaxf(dq[r] * smo[tp] + bmo[tp], 0.f);
                if constexpr (NOUT == 64) {     // fused: to wave-private LDS
                    *(unsigned*)&fp2[(quad * 4 + r) * 72 + tp * 32 + 2 * col] = pk2(ye, yo);
                } else {
                    int pp = pbase + quad * 4 + r;
                    *(unsigned*)&out[(size_t)pp * NOUT + tp * 32 + 2 * col] = pk2(ye, yo);
                }
            }
        }
    }

    // ---- fused k_out (NOUT==64): out = leaky(cb(f_pc2,mlp2) + cb(feature,sc))
    if constexpr (NOUT == 64) {
        bf16x8 a10 = *(const bf16x8*)&fp2[col * 72 + quad * 8];
        bf16x8 a11 = *(const bf16x8*)&fp2[col * 72 + 32 + quad * 8];
        const float* fr = &feature[(size_t)(pbase + col) * 32 + quad * 8];
        float4 u0 = *(const float4*)fr;
        float4 u1 = *(const float4*)(fr + 4);
        bf16x8 a2 = pack8(u0.x, u0.y, u0.z, u0.w, u1.x, u1.y, u1.z, u1.w);
        #pragma unroll
        for (int m = 0; m < 4; m++) {
            bf16x8 ke0 = *(const bf16x8*)&w2T[(m * 32 + col) * 88 + quad * 8];
            bf16x8 ke1 = *(const bf16x8*)&w2T[(m * 32 + col) * 88 + 32 + quad * 8];
            bf16x8 ko0 = *(const bf16x8*)&w2T[(m * 32 + 16 + col) * 88 + quad * 8];
            bf16x8 ko1 = *(const bf16x8*)&w2T[(m * 32 + 16 + col) * 88 + 32 + quad * 8];
            bf16x8 se  = *(const bf16x8*)&wsT[(m * 32 + col) * 40 + quad * 8];
            bf16x8 so  = *(const bf16x8*)&wsT[(m * 32 + 16 + col) * 40 + quad * 8];
            f32x4 de = mfma16(a11, ke1, mfma16(a10, ke0, z));
            f32x4 dq = mfma16(a11, ko1, mfma16(a10, ko0, z));
            f32x4 ee = mfma16(a2, se, z);
            f32x4 eo = mfma16(a2, so, z);
            int ce = m * 32 + 2 * col, co = ce + 1;
            float sse = s2[ce], sso = s2[co];
            float ste = ssc[ce], sto = ssc[co];
            float bbe = b2[ce] + bsc[ce], bbo = b2[co] + bsc[co];
            #pragma unroll
            for (int r = 0; r < 4; r++) {
                float ye = de[r] * sse + ee[r] * ste + bbe;
                float yo = dq[r] * sso + eo[r] * sto + bbo;
                ye = ye > 0.f ? ye : 0.2f * ye;
                yo = yo > 0.f ? yo : 0.2f * yo;
                *(float2*)&outF[(size_t)(pbase + quad * 4 + r) * 128 + m * 32 + 2 * col] =
                    make_float2(ye, yo);
            }
        }
    }
}

// ---------------------------------------------------------------- launch
extern "C" void kernel_launch(void* const* d_in, const int* in_sizes, int n_in,
                              void* d_out, int out_size, void* d_ws, size_t ws_size,
                              hipStream_t stream) {
    const float* feature = (const float*)d_in[0];
    const float* xyz     = (const float*)d_in[1];
    const int*   nidx    = (const int*)d_in[2];
    const float* w_mlp1 = (const float*)d_in[3];
    const float* s_mlp1 = (const float*)d_in[4];
    const float* b_mlp1 = (const float*)d_in[5];
    const float* w_lfa1 = (const float*)d_in[6];
    const float* s_lfa1 = (const float*)d_in[7];
    const float* b_lfa1 = (const float*)d_in[8];
    const float* w_att1_fc  = (const float*)d_in[9];
    const float* w_att1_mlp = (const float*)d_in[10];
    const float* s_att1_mlp = (const float*)d_in[11];
    const float* b_att1_mlp = (const float*)d_in[12];
    const float* w_lfa2 = (const float*)d_in[13];
    const float* s_lfa2 = (const float*)d_in[14];
    const float* b_lfa2 = (const float*)d_in[15];
    const float* w_att2_fc  = (const float*)d_in[16];
    const float* w_att2_mlp = (const float*)d_in[17];
    const float* s_att2_mlp = (const float*)d_in[18];
    const float* b_att2_mlp = (const float*)d_in[19];
    const float* w_mlp2 = (const float*)d_in[20];
    const float* s_mlp2 = (const float*)d_in[21];
    const float* b_mlp2 = (const float*)d_in[22];
    const float* w_sc = (const float*)d_in[23];
    const float* s_sc = (const float*)d_in[24];
    const float* b_sc = (const float*)d_in[25];

    unsigned short* f_pc  = (unsigned short*)d_ws;               // [BNPTS][32] bf16
    unsigned short* f_agg = f_pc  + (size_t)BNPTS * 32;          // [BNPTS][32] bf16
    unsigned short* f_pc2 = f_agg + (size_t)BNPTS * 32;          // [BNPTS][64] bf16 (unused now)
    unsigned short* pkw   = f_pc2 + (size_t)BNPTS * 64;          // packed weights
    float*          xyz4  = (float*)(pkw + PK_TOTAL);            // [BNPTS] float4
    float* out = (float*)d_out;

    k_prep<<<8, 256, 0, stream>>>(
        w_mlp1, w_att1_fc, w_att2_fc,
        w_lfa1, s_lfa1, b_lfa1, w_lfa2,
        w_att1_mlp, w_att2_mlp, w_mlp2, w_sc, pkw);
    k_mlp1<<<BNPTS / 256, 256, 0, stream>>>(feature, pkw, s_mlp1, b_mlp1, xyz, xyz4, f_pc);
    k_att<32, false><<<BNPTS / 64, 256, 0, stream>>>(
        xyz4, nidx, f_pc,
        pkw + PK_L1, pkw + PK_L1,            // lfa2 slots unused
        s_lfa1, b_lfa1,
        pkw + PK_FC1, pkw + PK_M1, s_att1_mlp, b_att1_mlp, f_agg,
        feature, pkw + PK_W2, pkw + PK_WS,   // fused-tail args unused for NOUT=32
        s_mlp2, b_mlp2, s_sc, b_sc, out);
    k_att<64, true><<<BNPTS / 64, 256, 0, stream>>>(
        xyz4, nidx, f_agg,
        pkw + PK_L1, pkw + PK_L2,
        s_lfa2, b_lfa2,
        pkw + PK_FC2, pkw + PK_M2, s_att2_mlp, b_att2_mlp, f_pc2,
        feature, pkw + PK_W2, pkw + PK_WS,
        s_mlp2, b_mlp2, s_sc, b_sc, out);
}